// Round 9
// baseline (87.886 us; speedup 1.0000x reference)
//
#include <hip/hip_runtime.h>
#include <math.h>

// Gaussians covariance, MI355X. cov = s^2 * I exactly (isotropic scales,
// R orthogonal) -> problem is the exact 3-NN search over N^2 pairs.
//
// R9 (vs R8: ~41.7us controllable; elimination from the R7->R8 null result
// says knn_finalize (~25us) was the pig, not cellmin's stores):
//  - BLOCKED cells: pass-A B-staging permuted so MFMA column m holds j's
//    [m*32, m*32+32) of the chunk -> a cell is 32 CONSECUTIVE points; the
//    rescan reads 6 cache lines per cell instead of 32 (300MB -> ~43MB of
//    L2 sector traffic). LDS store order unchanged (conflict-free); only
//    the j index computation changes.
//  - wave-parallel finalize: 1536 single-wave blocks, 8 i/wave x 8 workers;
//    48-cell scans per worker, __shfl_xor butterfly top-4 merge (3 levels),
//    exact diff-form rescan (4 consecutive j's per worker per cell),
//    second butterfly, coalesced s^2*I store. No sub-wave serial phases.
//  - pass A core unchanged: mfma_f32_16x16x32_f16 computes 16x16 tiles of
//    offset-half-distances qj - xi.xj via compensated fp16 (products exact
//    in fp32; selection error ~4e-5), 1 v_min/pair, cell == D column.
// NOTE: ~44us of the timed window is the harness's 256MiB d_ws poison fill.

#define N_PTS 12288
#define CHUNK 512               // j's per chunk
#define NCH   (N_PTS / CHUNK)   // 24 chunks
#define NCELL (NCH * 16)        // 384 cells of 32 consecutive j's
#define CELLJ 32
#define IBLK  256               // i's per pass-A block
#define NIB   (N_PTS / IBLK)    // 48
#define TSTR  257               // LDS transpose stride (dwords)

typedef _Float16 half8 __attribute__((ext_vector_type(8)));
typedef float    f32x4 __attribute__((ext_vector_type(4)));

__device__ __forceinline__ void ins4(float d, float& a0, float& a1,
                                     float& a2, float& a3) {
    // insert d into sorted a0<=a1<=a2<=a3, keep 4 smallest (4 VALU)
    const float n0 = fminf(a0, d);
    const float n1 = __builtin_amdgcn_fmed3f(a0, a1, d);
    const float n2 = __builtin_amdgcn_fmed3f(a1, a2, d);
    const float n3 = __builtin_amdgcn_fmed3f(a2, a3, d);
    a0 = n0; a1 = n1; a2 = n2; a3 = n3;
}

__global__ __launch_bounds__(256) void cellmin_mfma(
    const float* __restrict__ pts, unsigned* __restrict__ ws)
{
    // 32KB shared: B fragments during the MFMA loop, then reused as the
    // [16 cells][256 i] transpose buffer (stride TSTR) for coalesced stores
    __shared__ __align__(16) unsigned char shmem[32 * 64 * 8 * 2];
    _Float16* sB = (_Float16*)shmem;
    float*    sT = (float*)shmem;

    const int t    = threadIdx.x;
    const int iblk = blockIdx.x * IBLK;
    const int g    = blockIdx.y;           // chunk 0..23

    // ---- stage this chunk's B fragments (hi/lo split + qh/ql) ----
    // iterate (col = idx&15, b = idx>>4): consecutive t -> consecutive col
    // -> conflict-free LDS stores.  BLOCKED cell map: col m holds
    // j = g*CHUNK + m*32 + b  (cell m = 32 consecutive j's).
    for (int idx = t; idx < CHUNK; idx += 256) {
        const int col = idx & 15, b = idx >> 4;
        const int j = g * CHUNK + col * 32 + b;
        const float x = pts[3 * j + 0], y = pts[3 * j + 1], z = pts[3 * j + 2];
        const _Float16 bhx = (_Float16)x, bhy = (_Float16)y, bhz = (_Float16)z;
        const _Float16 blx = (_Float16)(x - (float)bhx);
        const _Float16 bly = (_Float16)(y - (float)bhy);
        const _Float16 blz = (_Float16)(z - (float)bhz);
        const float q = 0.5f * fmaf(z, z, fmaf(y, y, x * x));
        const _Float16 qh = (_Float16)q;
        const _Float16 ql = (_Float16)(q - (float)qh);
        half8 s0;   // k0-7: -bh(xyz) (vs ah), -bh(xyz) (vs al), -bl(x,y)
        s0[0] = -bhx; s0[1] = -bhy; s0[2] = -bhz;
        s0[3] = -bhx; s0[4] = -bhy; s0[5] = -bhz;
        s0[6] = -blx; s0[7] = -bly;
        half8 s1;   // k8-15: -bl_z (vs ah_z), qh, ql (vs 1), zeros
        s1 = (_Float16)0;
        s1[0] = -blz; s1[1] = qh; s1[2] = ql;
        *(half8*)&sB[(b * 64 + col) * 8]      = s0;
        *(half8*)&sB[(b * 64 + 16 + col) * 8] = s1;
    }
    {   // zero-fill quads 2-3 slots
        half8 zz = (_Float16)0;
        for (int s = t; s < 32 * 32; s += 256)
            *(half8*)&sB[((s >> 5) * 64 + 32 + (s & 31)) * 8] = zz;
    }

    // own-i q (thread t owns i = iblk + t for the store phase)
    float qi_t;
    {
        const float x = pts[3 * (iblk + t) + 0];
        const float y = pts[3 * (iblk + t) + 1];
        const float z = pts[3 * (iblk + t) + 2];
        qi_t = 0.5f * fmaf(z, z, fmaf(y, y, x * x));
    }

    // ---- A fragments: wave w owns i-tiles 4w+rr (16 i's each) ----
    const int lane = t & 63;
    const int w    = t >> 6;
    const int m    = lane & 15;    // A row / D col == cell lane
    const int quad = lane >> 4;

    half8 afr[4];
    f32x4 mn[4];
    #pragma unroll
    for (int rr = 0; rr < 4; ++rr) {
        const int i = iblk + (4 * w + rr) * 16 + m;
        const float x = pts[3 * i + 0], y = pts[3 * i + 1], z = pts[3 * i + 2];
        const _Float16 ahx = (_Float16)x, ahy = (_Float16)y, ahz = (_Float16)z;
        const _Float16 alx = (_Float16)(x - (float)ahx);
        const _Float16 aly = (_Float16)(y - (float)ahy);
        const _Float16 alz = (_Float16)(z - (float)ahz);
        half8 a = (_Float16)0;
        if (quad == 0) {        // k0-7: ah(xyz), al(xyz), ah(x,y)
            a[0] = ahx; a[1] = ahy; a[2] = ahz;
            a[3] = alx; a[4] = aly; a[5] = alz;
            a[6] = ahx; a[7] = ahy;
        } else if (quad == 1) { // k8-15: ah_z, 1, 1, zeros
            a[0] = ahz; a[1] = (_Float16)1.0f; a[2] = (_Float16)1.0f;
        }
        afr[rr] = a;
        mn[rr] = INFINITY;
    }
    __syncthreads();

    const f32x4 zero4 = 0.0f;
    #pragma unroll 4
    for (int b = 0; b < 32; ++b) {
        const half8 bf = *(const half8*)&sB[(b * 64 + lane) * 8];
        #pragma unroll
        for (int rr = 0; rr < 4; ++rr) {
            const f32x4 d = __builtin_amdgcn_mfma_f32_16x16x32_f16(
                afr[rr], bf, zero4, 0, 0, 0);
            mn[rr][0] = fminf(mn[rr][0], d[0]);
            mn[rr][1] = fminf(mn[rr][1], d[1]);
            mn[rr][2] = fminf(mn[rr][2], d[2]);
            mn[rr][3] = fminf(mn[rr][3], d[3]);
        }
    }
    __syncthreads();   // done with sB; reuse as transpose buffer

    // ---- transpose through LDS: sT[cell][i_loc], stride TSTR ----
    #pragma unroll
    for (int rr = 0; rr < 4; ++rr) {
        const int rowb = (4 * w + rr) * 16 + quad * 4;   // D row base
        #pragma unroll
        for (int reg = 0; reg < 4; ++reg)
            sT[m * TSTR + rowb + reg] = mn[rr][reg];
    }
    __syncthreads();

    // ---- coalesced packed stores: 16 x 1KB per-cell rows ----
    #pragma unroll
    for (int c = 0; c < 16; ++c) {
        const float v = sT[c * TSTR + t] + qi_t;
        const unsigned cid = (unsigned)(g * 16 + c);     // wave-uniform
        ws[(size_t)cid * N_PTS + iblk + t] =
            (__float_as_uint(v) & ~511u) | cid;
    }
}

// 1536 single-wave blocks: 8 i's per wave, 8 workers per i.
__global__ __launch_bounds__(64) void knn_finalize(
    const unsigned* __restrict__ ws, const float* __restrict__ pts,
    float* __restrict__ out)
{
    __shared__ float sS[8];
    const int lane  = threadIdx.x;
    const int il    = lane & 7;          // i_loc 0..7
    const int w     = lane >> 3;         // worker 0..7
    const int ibase = blockIdx.x * 8;
    const int i     = ibase + il;

    // phase 1: worker w scans cells [48w, 48w+48) of the packed minima
    float c0 = INFINITY, c1 = INFINITY, c2 = INFINITY, c3 = INFINITY;
    #pragma unroll 4
    for (int c = w * 48; c < w * 48 + 48; ++c) {
        const float v = __uint_as_float(ws[(size_t)c * N_PTS + i]);
        ins4(v, c0, c1, c2, c3);
    }

    // phase 2: butterfly merge across the worker dimension (lane bits 3-5)
    #pragma unroll
    for (int mask = 8; mask < 64; mask <<= 1) {
        const float p0 = __shfl_xor(c0, mask);
        const float p1 = __shfl_xor(c1, mask);
        const float p2 = __shfl_xor(c2, mask);
        const float p3 = __shfl_xor(c3, mask);
        ins4(p0, c0, c1, c2, c3);
        ins4(p1, c0, c1, c2, c3);
        ins4(p2, c0, c1, c2, c3);
        ins4(p3, c0, c1, c2, c3);
    }
    // all lanes of i-group il now hold the global top-4 cells for i

    const float px = pts[3 * i + 0];
    const float py = pts[3 * i + 1];
    const float pz = pts[3 * i + 2];

    // phase 3: exact diff-form rescan; worker w takes 4 consecutive j's
    // per candidate cell (blocked cells: cellbase .. cellbase+31 contiguous)
    float b0 = INFINITY, b1 = INFINITY, b2 = INFINITY, b3 = INFINITY;
    const unsigned cells[4] = {
        __float_as_uint(c0) & 511u, __float_as_uint(c1) & 511u,
        __float_as_uint(c2) & 511u, __float_as_uint(c3) & 511u };
    #pragma unroll
    for (int q = 0; q < 4; ++q) {
        const int cid  = (int)cells[q];
        const int jb   = (cid >> 4) * CHUNK + (cid & 15) * CELLJ + w * 4;
        #pragma unroll
        for (int n = 0; n < 4; ++n) {
            const int j = jb + n;
            const float dx = px - pts[3 * j + 0];
            const float dy = py - pts[3 * j + 1];
            const float dz = pz - pts[3 * j + 2];
            const float d2 = fmaf(dz, dz, fmaf(dy, dy, dx * dx));
            ins4(d2, b0, b1, b2, b3);        // j==i gives exactly 0
        }
    }

    // phase 4: butterfly merge of the rescan top-4s
    #pragma unroll
    for (int mask = 8; mask < 64; mask <<= 1) {
        const float p0 = __shfl_xor(b0, mask);
        const float p1 = __shfl_xor(b1, mask);
        const float p2 = __shfl_xor(b2, mask);
        const float p3 = __shfl_xor(b3, mask);
        ins4(p0, b0, b1, b2, b3);
        ins4(p1, b0, b1, b2, b3);
        ins4(p2, b0, b1, b2, b3);
        ins4(p3, b0, b1, b2, b3);
    }

    // b0 == 0 is the self pair; b1..b3 are the true 3-NN squared distances
    if (w == 0) {
        const float d0 = sqrtf(b1);
        const float d1 = sqrtf(b2);
        const float d2 = sqrtf(b3);
        float mean = fmaxf((d0 + d1 + d2) * (1.0f / 3.0f), 1e-5f);
        const float s = 0.001f * mean;
        sS[il] = s * s;
    }
    __syncthreads();

    // coalesced s^2 * I store: 72 floats for this wave's 8 i's
    for (int k = lane; k < 72; k += 64) {
        const int i2 = k / 9, r = k % 9;
        const float v = (r == 0 || r == 4 || r == 8) ? sS[i2] : 0.0f;
        out[(size_t)(ibase + i2) * 9 + r] = v;
    }
}

extern "C" void kernel_launch(void* const* d_in, const int* in_sizes, int n_in,
                              void* d_out, int out_size, void* d_ws, size_t ws_size,
                              hipStream_t stream) {
    const float* pts = (const float*)d_in[0];   // (N, 3) float32
    // d_in[1] = quaternions: algebraically irrelevant (cov = s^2 * I)
    unsigned* ws = (unsigned*)d_ws;             // 384 * 12288 * 4B = 18.9 MB
    float*    out = (float*)d_out;              // (N, 3, 3) float32

    cellmin_mfma<<<dim3(NIB, NCH), dim3(256), 0, stream>>>(pts, ws);
    knn_finalize<<<dim3(N_PTS / 8), dim3(64), 0, stream>>>(ws, pts, out);
}

// Round 10
// 75.191 us; speedup vs baseline: 1.1688x; 1.1688x over previous
//
#include <hip/hip_runtime.h>
#include <math.h>

// Gaussians covariance, MI355X. cov = s^2 * I exactly (isotropic scales,
// R orthogonal) -> problem is the exact 3-NN search over N^2 pairs.
//
// R10 (decisive experiment; R8->R9 finalize rewrite was neutral, so the
// ~30us my models can't place is in ONE of the two kernels — shrink the
// inter-kernel interface 16x and see which side moves):
//  - pass A epilogue: after the LDS transpose, each thread reduces its i's
//    16 cell minima (already packed with 9-bit cell ids) to a top-4 in
//    registers and stores ONE float4 per (i, chunk). ws: 18.9 -> 4.7 MB.
//  - finalize phase 1: 3 coalesced float4 loads per lane (was 48 scattered
//    dwords). Rest identical to R9: 8 workers/i butterfly merge, exact
//    diff-form rescan of top-4 blocked cells, second butterfly, s^2*I.
//  - pass A core unchanged: mfma_f32_16x16x32_f16 tiles of qj - xi.xj via
//    compensated fp16 (products exact in fp32), 1 v_min/pair, blocked
//    cells (col m = 32 consecutive j's).
// NOTE: ~42-46us of the timed window is the harness's 256MiB ws poison fill.

#define N_PTS 12288
#define CHUNK 512               // j's per chunk
#define NCH   (N_PTS / CHUNK)   // 24 chunks
#define CELLJ 32                // consecutive j's per cell; 16 cells/chunk
#define IBLK  256               // i's per pass-A block
#define NIB   (N_PTS / IBLK)    // 48
#define TSTR  257               // LDS transpose stride (dwords)

typedef _Float16 half8 __attribute__((ext_vector_type(8)));
typedef float    f32x4 __attribute__((ext_vector_type(4)));

__device__ __forceinline__ void ins4(float d, float& a0, float& a1,
                                     float& a2, float& a3) {
    // insert d into sorted a0<=a1<=a2<=a3, keep 4 smallest (4 VALU)
    const float n0 = fminf(a0, d);
    const float n1 = __builtin_amdgcn_fmed3f(a0, a1, d);
    const float n2 = __builtin_amdgcn_fmed3f(a1, a2, d);
    const float n3 = __builtin_amdgcn_fmed3f(a2, a3, d);
    a0 = n0; a1 = n1; a2 = n2; a3 = n3;
}

__global__ __launch_bounds__(256) void cellmin_mfma(
    const float* __restrict__ pts, float4* __restrict__ ws4)
{
    // 32KB shared: B fragments during the MFMA loop, then reused as the
    // [16 cells][256 i] transpose buffer (stride TSTR)
    __shared__ __align__(16) unsigned char shmem[32 * 64 * 8 * 2];
    _Float16* sB = (_Float16*)shmem;
    float*    sT = (float*)shmem;

    const int t    = threadIdx.x;
    const int iblk = blockIdx.x * IBLK;
    const int g    = blockIdx.y;           // chunk 0..23

    // ---- stage this chunk's B fragments (hi/lo split + qh/ql) ----
    // BLOCKED cell map: col m holds j = g*CHUNK + m*32 + b
    for (int idx = t; idx < CHUNK; idx += 256) {
        const int col = idx & 15, b = idx >> 4;
        const int j = g * CHUNK + col * 32 + b;
        const float x = pts[3 * j + 0], y = pts[3 * j + 1], z = pts[3 * j + 2];
        const _Float16 bhx = (_Float16)x, bhy = (_Float16)y, bhz = (_Float16)z;
        const _Float16 blx = (_Float16)(x - (float)bhx);
        const _Float16 bly = (_Float16)(y - (float)bhy);
        const _Float16 blz = (_Float16)(z - (float)bhz);
        const float q = 0.5f * fmaf(z, z, fmaf(y, y, x * x));
        const _Float16 qh = (_Float16)q;
        const _Float16 ql = (_Float16)(q - (float)qh);
        half8 s0;   // k0-7: -bh(xyz) (vs ah), -bh(xyz) (vs al), -bl(x,y)
        s0[0] = -bhx; s0[1] = -bhy; s0[2] = -bhz;
        s0[3] = -bhx; s0[4] = -bhy; s0[5] = -bhz;
        s0[6] = -blx; s0[7] = -bly;
        half8 s1;   // k8-15: -bl_z (vs ah_z), qh, ql (vs 1), zeros
        s1 = (_Float16)0;
        s1[0] = -blz; s1[1] = qh; s1[2] = ql;
        *(half8*)&sB[(b * 64 + col) * 8]      = s0;
        *(half8*)&sB[(b * 64 + 16 + col) * 8] = s1;
    }
    {   // zero-fill quads 2-3 slots
        half8 zz = (_Float16)0;
        for (int s = t; s < 32 * 32; s += 256)
            *(half8*)&sB[((s >> 5) * 64 + 32 + (s & 31)) * 8] = zz;
    }

    // own-i q (thread t owns i = iblk + t for the reduce/store phase)
    float qi_t;
    {
        const float x = pts[3 * (iblk + t) + 0];
        const float y = pts[3 * (iblk + t) + 1];
        const float z = pts[3 * (iblk + t) + 2];
        qi_t = 0.5f * fmaf(z, z, fmaf(y, y, x * x));
    }

    // ---- A fragments: wave w owns i-tiles 4w+rr (16 i's each) ----
    const int lane = t & 63;
    const int w    = t >> 6;
    const int m    = lane & 15;    // A row / D col == cell lane
    const int quad = lane >> 4;

    half8 afr[4];
    f32x4 mn[4];
    #pragma unroll
    for (int rr = 0; rr < 4; ++rr) {
        const int i = iblk + (4 * w + rr) * 16 + m;
        const float x = pts[3 * i + 0], y = pts[3 * i + 1], z = pts[3 * i + 2];
        const _Float16 ahx = (_Float16)x, ahy = (_Float16)y, ahz = (_Float16)z;
        const _Float16 alx = (_Float16)(x - (float)ahx);
        const _Float16 aly = (_Float16)(y - (float)ahy);
        const _Float16 alz = (_Float16)(z - (float)ahz);
        half8 a = (_Float16)0;
        if (quad == 0) {        // k0-7: ah(xyz), al(xyz), ah(x,y)
            a[0] = ahx; a[1] = ahy; a[2] = ahz;
            a[3] = alx; a[4] = aly; a[5] = alz;
            a[6] = ahx; a[7] = ahy;
        } else if (quad == 1) { // k8-15: ah_z, 1, 1, zeros
            a[0] = ahz; a[1] = (_Float16)1.0f; a[2] = (_Float16)1.0f;
        }
        afr[rr] = a;
        mn[rr] = INFINITY;
    }
    __syncthreads();

    const f32x4 zero4 = 0.0f;
    #pragma unroll 4
    for (int b = 0; b < 32; ++b) {
        const half8 bf = *(const half8*)&sB[(b * 64 + lane) * 8];
        #pragma unroll
        for (int rr = 0; rr < 4; ++rr) {
            const f32x4 d = __builtin_amdgcn_mfma_f32_16x16x32_f16(
                afr[rr], bf, zero4, 0, 0, 0);
            mn[rr][0] = fminf(mn[rr][0], d[0]);
            mn[rr][1] = fminf(mn[rr][1], d[1]);
            mn[rr][2] = fminf(mn[rr][2], d[2]);
            mn[rr][3] = fminf(mn[rr][3], d[3]);
        }
    }
    __syncthreads();   // done with sB; reuse as transpose buffer

    // ---- transpose through LDS: sT[cell][i_loc], stride TSTR ----
    #pragma unroll
    for (int rr = 0; rr < 4; ++rr) {
        const int rowb = (4 * w + rr) * 16 + quad * 4;   // D row base
        #pragma unroll
        for (int reg = 0; reg < 4; ++reg)
            sT[m * TSTR + rowb + reg] = mn[rr][reg];
    }
    __syncthreads();

    // ---- per-i reduce: 16 cells -> top-4 packed, ONE float4 store ----
    float t0 = INFINITY, t1 = INFINITY, t2 = INFINITY, t3 = INFINITY;
    #pragma unroll
    for (int c = 0; c < 16; ++c) {
        const float v = sT[c * TSTR + t] + qi_t;
        const unsigned cid = (unsigned)(g * 16 + c);
        const float pv = __uint_as_float((__float_as_uint(v) & ~511u) | cid);
        ins4(pv, t0, t1, t2, t3);
    }
    ws4[(size_t)g * N_PTS + (iblk + t)] = make_float4(t0, t1, t2, t3);
}

// 1536 single-wave blocks: 8 i's per wave, 8 workers per i.
__global__ __launch_bounds__(64) void knn_finalize(
    const float4* __restrict__ ws4, const float* __restrict__ pts,
    float* __restrict__ out)
{
    __shared__ float sS[8];
    const int lane  = threadIdx.x;
    const int il    = lane & 7;          // i_loc 0..7
    const int w     = lane >> 3;         // worker 0..7
    const int ibase = blockIdx.x * 8;
    const int i     = ibase + il;

    // phase 1: worker w scans chunks [3w, 3w+3): 3 coalesced float4 loads
    float c0 = INFINITY, c1 = INFINITY, c2 = INFINITY, c3 = INFINITY;
    #pragma unroll
    for (int k = 0; k < 3; ++k) {
        const float4 v = ws4[(size_t)(3 * w + k) * N_PTS + i];
        ins4(v.x, c0, c1, c2, c3);
        ins4(v.y, c0, c1, c2, c3);
        ins4(v.z, c0, c1, c2, c3);
        ins4(v.w, c0, c1, c2, c3);
    }

    // phase 2: butterfly merge across the worker dimension (lane bits 3-5)
    #pragma unroll
    for (int mask = 8; mask < 64; mask <<= 1) {
        const float p0 = __shfl_xor(c0, mask);
        const float p1 = __shfl_xor(c1, mask);
        const float p2 = __shfl_xor(c2, mask);
        const float p3 = __shfl_xor(c3, mask);
        ins4(p0, c0, c1, c2, c3);
        ins4(p1, c0, c1, c2, c3);
        ins4(p2, c0, c1, c2, c3);
        ins4(p3, c0, c1, c2, c3);
    }
    // all lanes of i-group il now hold the global top-4 cells for i

    const float px = pts[3 * i + 0];
    const float py = pts[3 * i + 1];
    const float pz = pts[3 * i + 2];

    // phase 3: exact diff-form rescan; worker w takes 4 consecutive j's
    // per candidate cell (blocked cells: cellbase .. cellbase+31 contiguous)
    float b0 = INFINITY, b1 = INFINITY, b2 = INFINITY, b3 = INFINITY;
    const unsigned cells[4] = {
        __float_as_uint(c0) & 511u, __float_as_uint(c1) & 511u,
        __float_as_uint(c2) & 511u, __float_as_uint(c3) & 511u };
    #pragma unroll
    for (int q = 0; q < 4; ++q) {
        const int cid = (int)cells[q];
        const int jb  = (cid >> 4) * CHUNK + (cid & 15) * CELLJ + w * 4;
        #pragma unroll
        for (int n = 0; n < 4; ++n) {
            const int j = jb + n;
            const float dx = px - pts[3 * j + 0];
            const float dy = py - pts[3 * j + 1];
            const float dz = pz - pts[3 * j + 2];
            const float d2 = fmaf(dz, dz, fmaf(dy, dy, dx * dx));
            ins4(d2, b0, b1, b2, b3);        // j==i gives exactly 0
        }
    }

    // phase 4: butterfly merge of the rescan top-4s
    #pragma unroll
    for (int mask = 8; mask < 64; mask <<= 1) {
        const float p0 = __shfl_xor(b0, mask);
        const float p1 = __shfl_xor(b1, mask);
        const float p2 = __shfl_xor(b2, mask);
        const float p3 = __shfl_xor(b3, mask);
        ins4(p0, b0, b1, b2, b3);
        ins4(p1, b0, b1, b2, b3);
        ins4(p2, b0, b1, b2, b3);
        ins4(p3, b0, b1, b2, b3);
    }

    // b0 == 0 is the self pair; b1..b3 are the true 3-NN squared distances
    if (w == 0) {
        const float d0 = sqrtf(b1);
        const float d1 = sqrtf(b2);
        const float d2 = sqrtf(b3);
        float mean = fmaxf((d0 + d1 + d2) * (1.0f / 3.0f), 1e-5f);
        const float s = 0.001f * mean;
        sS[il] = s * s;
    }
    __syncthreads();

    // coalesced s^2 * I store: 72 floats for this wave's 8 i's
    for (int k = lane; k < 72; k += 64) {
        const int i2 = k / 9, r = k % 9;
        const float v = (r == 0 || r == 4 || r == 8) ? sS[i2] : 0.0f;
        out[(size_t)(ibase + i2) * 9 + r] = v;
    }
}

extern "C" void kernel_launch(void* const* d_in, const int* in_sizes, int n_in,
                              void* d_out, int out_size, void* d_ws, size_t ws_size,
                              hipStream_t stream) {
    const float* pts = (const float*)d_in[0];   // (N, 3) float32
    // d_in[1] = quaternions: algebraically irrelevant (cov = s^2 * I)
    float4* ws4 = (float4*)d_ws;                // 24 * 12288 * 16B = 4.7 MB
    float*  out = (float*)d_out;                // (N, 3, 3) float32

    cellmin_mfma<<<dim3(NIB, NCH), dim3(256), 0, stream>>>(pts, ws4);
    knn_finalize<<<dim3(N_PTS / 8), dim3(64), 0, stream>>>(ws4, pts, out);
}

// Round 11
// 71.572 us; speedup vs baseline: 1.2279x; 1.0506x over previous
//
#include <hip/hip_runtime.h>
#include <math.h>

// Gaussians covariance, MI355X. cov = s^2 * I exactly (isotropic scales,
// R orthogonal) -> problem is the exact 3-NN search over N^2 pairs.
//
// R11 (vs R10: ~35us controllable, cellmin ~2.5x over its model):
//  - mfma_f32_32x32x16_f16 instead of 16x16x32: K=16 fits the 11
//    compensated-fp16 slots (31% waste vs 66%), and 32x32 gives 31.7
//    pairs/SIMD-cyc vs 13.2 -> MFMA cost per block halves; now balanced
//    against the v_min stream on the separate VALU pipe.
//  - cells: (chunk, col) = 32 cells x 16 CONSECUTIVE j's, 768 total;
//    10-bit id packed into the mantissa (2^-13 selection perturbation,
//    ~1000x under threshold; exact diff-form rescan unchanged).
//  - lane layouts (verified 32x32 pattern): A row=lane&31 k=(lane>>5)*8+idx,
//    B col=lane&31 same k, C/D row=(reg&3)+8*(reg>>2)+4*(lane>>5).
//  - sB 16KB, transpose 33KB union -> 4 blocks/CU (__launch_bounds__(256,4)).
// NOTE: ~40us of the timed window is the harness's 256MiB ws poison fill.

#define N_PTS 12288
#define CHUNK 512               // j's per chunk
#define NCH   (N_PTS / CHUNK)   // 24 chunks
#define CELLJ 16                // consecutive j's per cell; 32 cells/chunk
#define IBLK  256               // i's per pass-A block
#define NIB   (N_PTS / IBLK)    // 48
#define TSTR  257               // LDS transpose stride (dwords)
#define CMASK 1023u             // 10-bit cell id

typedef _Float16 half8  __attribute__((ext_vector_type(8)));
typedef float    f32x16 __attribute__((ext_vector_type(16)));

__device__ __forceinline__ void ins4(float d, float& a0, float& a1,
                                     float& a2, float& a3) {
    // insert d into sorted a0<=a1<=a2<=a3, keep 4 smallest (4 VALU)
    const float n0 = fminf(a0, d);
    const float n1 = __builtin_amdgcn_fmed3f(a0, a1, d);
    const float n2 = __builtin_amdgcn_fmed3f(a1, a2, d);
    const float n3 = __builtin_amdgcn_fmed3f(a2, a3, d);
    a0 = n0; a1 = n1; a2 = n2; a3 = n3;
}

__global__ __launch_bounds__(256, 4) void cellmin_mfma(
    const float* __restrict__ pts, float4* __restrict__ ws4)
{
    // union: sB (16 b-iters x 64 lane-slots x 8 halves = 16KB) during MFMA,
    // then sT (32 cells x 256 i, stride TSTR = 32.9KB) for the transpose
    __shared__ __align__(16) unsigned char shmem[32 * TSTR * 4];
    _Float16* sB = (_Float16*)shmem;
    float*    sT = (float*)shmem;

    const int t    = threadIdx.x;
    const int iblk = blockIdx.x * IBLK;
    const int g    = blockIdx.y;           // chunk 0..23

    // ---- stage B fragments: col c holds j = g*512 + c*16 + b (blocked) ----
    // K slots (h=0): k0-2 = -bh(xyz) (vs ah), k3-5 = -bh(xyz) (vs al),
    //                k6-7 = -bl(x,y) (vs ah)
    //        (h=1): k8 = -bl_z (vs ah_z), k9 = qh, k10 = ql (vs 1), rest 0
    for (int idx = t; idx < CHUNK; idx += 256) {
        const int col = idx & 31, b = idx >> 5;
        const int j = g * CHUNK + col * CELLJ + b;
        const float x = pts[3 * j + 0], y = pts[3 * j + 1], z = pts[3 * j + 2];
        const _Float16 bhx = (_Float16)x, bhy = (_Float16)y, bhz = (_Float16)z;
        const _Float16 blx = (_Float16)(x - (float)bhx);
        const _Float16 bly = (_Float16)(y - (float)bhy);
        const _Float16 blz = (_Float16)(z - (float)bhz);
        const float q = 0.5f * fmaf(z, z, fmaf(y, y, x * x));
        const _Float16 qh = (_Float16)q;
        const _Float16 ql = (_Float16)(q - (float)qh);
        half8 s0;
        s0[0] = -bhx; s0[1] = -bhy; s0[2] = -bhz;
        s0[3] = -bhx; s0[4] = -bhy; s0[5] = -bhz;
        s0[6] = -blx; s0[7] = -bly;
        half8 s1 = (_Float16)0;
        s1[0] = -blz; s1[1] = qh; s1[2] = ql;
        *(half8*)&sB[(b * 64 + col) * 8]      = s0;   // h=0 lanes
        *(half8*)&sB[(b * 64 + 32 + col) * 8] = s1;   // h=1 lanes
    }

    // own-i q (thread t owns i = iblk + t for the reduce/store phase)
    float qi_t;
    {
        const float x = pts[3 * (iblk + t) + 0];
        const float y = pts[3 * (iblk + t) + 1];
        const float z = pts[3 * (iblk + t) + 2];
        qi_t = 0.5f * fmaf(z, z, fmaf(y, y, x * x));
    }

    // ---- A fragments: wave w owns i-tiles 2w, 2w+1 (32 i's each) ----
    const int lane = t & 63;
    const int w    = t >> 6;
    const int m    = lane & 31;    // A row / D col == cell lane
    const int h    = lane >> 5;    // k-half

    half8  afr[2];
    f32x16 mn[2];
    #pragma unroll
    for (int tau = 0; tau < 2; ++tau) {
        const int i = iblk + (2 * w + tau) * 32 + m;
        const float x = pts[3 * i + 0], y = pts[3 * i + 1], z = pts[3 * i + 2];
        const _Float16 ahx = (_Float16)x, ahy = (_Float16)y, ahz = (_Float16)z;
        const _Float16 alx = (_Float16)(x - (float)ahx);
        const _Float16 aly = (_Float16)(y - (float)ahy);
        const _Float16 alz = (_Float16)(z - (float)ahz);
        half8 a = (_Float16)0;
        if (h == 0) {        // k0-7: ah(xyz), al(xyz), ah(x,y)
            a[0] = ahx; a[1] = ahy; a[2] = ahz;
            a[3] = alx; a[4] = aly; a[5] = alz;
            a[6] = ahx; a[7] = ahy;
        } else {             // k8-15: ah_z, 1, 1, zeros
            a[0] = ahz; a[1] = (_Float16)1.0f; a[2] = (_Float16)1.0f;
        }
        afr[tau] = a;
        mn[tau] = INFINITY;
    }
    __syncthreads();

    const f32x16 zero16 = 0.0f;
    #pragma unroll 4
    for (int b = 0; b < 16; ++b) {
        const half8 bf = *(const half8*)&sB[(b * 64 + lane) * 8];
        #pragma unroll
        for (int tau = 0; tau < 2; ++tau) {
            const f32x16 d = __builtin_amdgcn_mfma_f32_32x32x16_f16(
                afr[tau], bf, zero16, 0, 0, 0);
            #pragma unroll
            for (int r = 0; r < 16; ++r)
                mn[tau][r] = fminf(mn[tau][r], d[r]);
        }
    }
    __syncthreads();   // done with sB; reuse as transpose buffer

    // ---- transpose through LDS: sT[cell][i_loc], stride TSTR ----
    #pragma unroll
    for (int tau = 0; tau < 2; ++tau) {
        #pragma unroll
        for (int r = 0; r < 16; ++r) {
            const int row = (r & 3) + 8 * (r >> 2) + 4 * h;
            sT[m * TSTR + (2 * w + tau) * 32 + row] = mn[tau][r];
        }
    }
    __syncthreads();

    // ---- per-i reduce: 32 cells -> top-4 packed, ONE float4 store ----
    float t0 = INFINITY, t1 = INFINITY, t2 = INFINITY, t3 = INFINITY;
    #pragma unroll 8
    for (int c = 0; c < 32; ++c) {
        const float v = sT[c * TSTR + t] + qi_t;
        const unsigned cid = (unsigned)(g * 32 + c);
        const float pv = __uint_as_float((__float_as_uint(v) & ~CMASK) | cid);
        ins4(pv, t0, t1, t2, t3);
    }
    ws4[(size_t)g * N_PTS + (iblk + t)] = make_float4(t0, t1, t2, t3);
}

// 1536 single-wave blocks: 8 i's per wave, 8 workers per i.
__global__ __launch_bounds__(64) void knn_finalize(
    const float4* __restrict__ ws4, const float* __restrict__ pts,
    float* __restrict__ out)
{
    __shared__ float sS[8];
    const int lane  = threadIdx.x;
    const int il    = lane & 7;          // i_loc 0..7
    const int w     = lane >> 3;         // worker 0..7
    const int ibase = blockIdx.x * 8;
    const int i     = ibase + il;

    // phase 1: worker w scans chunks [3w, 3w+3): 3 coalesced float4 loads
    float c0 = INFINITY, c1 = INFINITY, c2 = INFINITY, c3 = INFINITY;
    #pragma unroll
    for (int k = 0; k < 3; ++k) {
        const float4 v = ws4[(size_t)(3 * w + k) * N_PTS + i];
        ins4(v.x, c0, c1, c2, c3);
        ins4(v.y, c0, c1, c2, c3);
        ins4(v.z, c0, c1, c2, c3);
        ins4(v.w, c0, c1, c2, c3);
    }

    // phase 2: butterfly merge across the worker dimension (lane bits 3-5)
    #pragma unroll
    for (int mask = 8; mask < 64; mask <<= 1) {
        const float p0 = __shfl_xor(c0, mask);
        const float p1 = __shfl_xor(c1, mask);
        const float p2 = __shfl_xor(c2, mask);
        const float p3 = __shfl_xor(c3, mask);
        ins4(p0, c0, c1, c2, c3);
        ins4(p1, c0, c1, c2, c3);
        ins4(p2, c0, c1, c2, c3);
        ins4(p3, c0, c1, c2, c3);
    }
    // all lanes of i-group il now hold the global top-4 cells for i

    const float px = pts[3 * i + 0];
    const float py = pts[3 * i + 1];
    const float pz = pts[3 * i + 2];

    // phase 3: exact diff-form rescan; worker w takes 2 consecutive j's
    // per candidate cell (16 consecutive j's per cell)
    float b0 = INFINITY, b1 = INFINITY, b2 = INFINITY, b3 = INFINITY;
    const unsigned cells[4] = {
        __float_as_uint(c0) & CMASK, __float_as_uint(c1) & CMASK,
        __float_as_uint(c2) & CMASK, __float_as_uint(c3) & CMASK };
    #pragma unroll
    for (int q = 0; q < 4; ++q) {
        const int cid = (int)cells[q];
        const int jb  = (cid >> 5) * CHUNK + (cid & 31) * CELLJ + w * 2;
        #pragma unroll
        for (int n = 0; n < 2; ++n) {
            const int j = jb + n;
            const float dx = px - pts[3 * j + 0];
            const float dy = py - pts[3 * j + 1];
            const float dz = pz - pts[3 * j + 2];
            const float d2 = fmaf(dz, dz, fmaf(dy, dy, dx * dx));
            ins4(d2, b0, b1, b2, b3);        // j==i gives exactly 0
        }
    }

    // phase 4: butterfly merge of the rescan top-4s
    #pragma unroll
    for (int mask = 8; mask < 64; mask <<= 1) {
        const float p0 = __shfl_xor(b0, mask);
        const float p1 = __shfl_xor(b1, mask);
        const float p2 = __shfl_xor(b2, mask);
        const float p3 = __shfl_xor(b3, mask);
        ins4(p0, b0, b1, b2, b3);
        ins4(p1, b0, b1, b2, b3);
        ins4(p2, b0, b1, b2, b3);
        ins4(p3, b0, b1, b2, b3);
    }

    // b0 == 0 is the self pair; b1..b3 are the true 3-NN squared distances
    if (w == 0) {
        const float d0 = sqrtf(b1);
        const float d1 = sqrtf(b2);
        const float d2 = sqrtf(b3);
        float mean = fmaxf((d0 + d1 + d2) * (1.0f / 3.0f), 1e-5f);
        const float s = 0.001f * mean;
        sS[il] = s * s;
    }
    __syncthreads();

    // coalesced s^2 * I store: 72 floats for this wave's 8 i's
    for (int k = lane; k < 72; k += 64) {
        const int i2 = k / 9, r = k % 9;
        const float v = (r == 0 || r == 4 || r == 8) ? sS[i2] : 0.0f;
        out[(size_t)(ibase + i2) * 9 + r] = v;
    }
}

extern "C" void kernel_launch(void* const* d_in, const int* in_sizes, int n_in,
                              void* d_out, int out_size, void* d_ws, size_t ws_size,
                              hipStream_t stream) {
    const float* pts = (const float*)d_in[0];   // (N, 3) float32
    // d_in[1] = quaternions: algebraically irrelevant (cov = s^2 * I)
    float4* ws4 = (float4*)d_ws;                // 24 * 12288 * 16B = 4.7 MB
    float*  out = (float*)d_out;                // (N, 3, 3) float32

    cellmin_mfma<<<dim3(NIB, NCH), dim3(256), 0, stream>>>(pts, ws4);
    knn_finalize<<<dim3(N_PTS / 8), dim3(64), 0, stream>>>(ws4, pts, out);
}